// Round 7
// baseline (198.897 us; speedup 1.0000x reference)
//
#include <hip/hip_runtime.h>

// BD-format field offsets (D = 512)
#define MARK_AX      0
#define OP_SHL       39   // elem 39 = 4*9 + 3  -> ballot[3] bit 9
#define OP_SHR       40   // elem 40 = 4*10 + 0 -> ballot[0] bit 10
#define ALU_LO       64   // lanes 16..19
#define ALU_HI       80   // lanes 20..23
#define AX_CARRY_LO  96   // lanes 24..27
#define OUTPUT_LO    128
#define OUTPUT_HI    144

constexpr int D = 512;

typedef float f32x4 __attribute__((ext_vector_type(4)));

// First hot index (0 if none) of the 16-wide field whose elements live in
// lanes [lane0, lane0+4). elem = 4*l + j  ->  field idx k = 4*(l-lane0) + j.
__device__ __forceinline__ int first_hot(const unsigned long long b[4], int lane0) {
    int best = 999;
    #pragma unroll
    for (int j = 0; j < 4; ++j) {
        unsigned nib = (unsigned)(b[j] >> lane0) & 0xFu;
        int cand = nib ? (4 * (__ffs(nib) - 1) + j) : 999;
        best = min(best, cand);
    }
    return (best >= 16) ? 0 : best;   // argmax-of-bool: 0 when no bit set
}

__device__ __forceinline__ void decode(const unsigned long long b[4],
                                       int& tlo, int& thi, float& amp) {
    const bool mark = (b[0] >> 0) & 1ull;    // elem 0
    const bool shl  = (b[3] >> 9) & 1ull;    // elem 39
    const bool shr  = (b[0] >> 10) & 1ull;   // elem 40

    const int lo = first_hot(b, 16);         // elems 64..79
    const int hi = first_hot(b, 20);         // elems 80..95
    const int sa = first_hot(b, 24);         // elems 96..111

    const int  val     = lo + 16 * hi;
    const bool act_shl = mark && shl;
    const bool act_shr = mark && shr && !shl;  // elif priority

    const int res = act_shl ? ((val << sa) & 0xFF)
                  : (act_shr ? (val >> sa) : 0);

    tlo = OUTPUT_LO + (res & 15);
    thi = OUTPUT_HI + (res >> 4);
    amp = (act_shl || act_shr) ? 2.0f : 0.0f;
}

__global__ __launch_bounds__(256) void shift_ffn_kernel(
    const float* __restrict__ x, float* __restrict__ out, int ntok)
{
    const int lane = threadIdx.x & 63;
    const int wid  = (blockIdx.x * blockDim.x + threadIdx.x) >> 6;
    const int nw   = (gridDim.x * blockDim.x) >> 6;
    const int e0   = 4 * lane;
    const int npair = ntok >> 1;              // ntok is even (8*32768)

    int p = wid;
    if (p >= npair) return;

    // Prologue: load first pair (2 tokens, 2 halves each); nt loads AND nt
    // stores (R2-R5 A/B: full L2 bypass both directions is fastest).
    const float* xt0 = x + (size_t)(2 * p) * D;
    f32x4 a0 = __builtin_nontemporal_load((const f32x4*)(xt0 + e0));
    f32x4 c0 = __builtin_nontemporal_load((const f32x4*)(xt0 + 256 + e0));
    f32x4 a1 = __builtin_nontemporal_load((const f32x4*)(xt0 + D + e0));
    f32x4 c1 = __builtin_nontemporal_load((const f32x4*)(xt0 + D + 256 + e0));

    while (true) {
        // Software pipeline: issue next iteration's 4 loads BEFORE consuming
        // the current ones. `more` is wave-uniform -> no divergence.
        const int pn = p + nw;
        const bool more = (pn < npair);
        f32x4 na0, nc0, na1, nc1;
        if (more) {
            const float* xn = x + (size_t)(2 * pn) * D;
            na0 = __builtin_nontemporal_load((const f32x4*)(xn + e0));
            nc0 = __builtin_nontemporal_load((const f32x4*)(xn + 256 + e0));
            na1 = __builtin_nontemporal_load((const f32x4*)(xn + D + e0));
            nc1 = __builtin_nontemporal_load((const f32x4*)(xn + D + 256 + e0));
        }

        // Ballot-based control gather: b[j] bit l == (elem 4l+j > 0.5)
        unsigned long long b0[4], b1[4];
        #pragma unroll
        for (int j = 0; j < 4; ++j) b0[j] = __ballot(a0[j] > 0.5f);
        #pragma unroll
        for (int j = 0; j < 4; ++j) b1[j] = __ballot(a1[j] > 0.5f);

        float* ot0 = out + (size_t)(2 * p) * D;

        // c-half stores are decode-independent: issue them first.
        __builtin_nontemporal_store(c0, (f32x4*)(ot0 + 256 + e0));
        __builtin_nontemporal_store(c1, (f32x4*)(ot0 + D + 256 + e0));

        int tlo0, thi0, tlo1, thi1; float amp0, amp1;
        decode(b0, tlo0, thi0, amp0);
        decode(b1, tlo1, thi1, amp1);

        #pragma unroll
        for (int j = 0; j < 4; ++j) {
            const int e = e0 + j;
            a0[j] += ((e == tlo0) ? amp0 : 0.0f) + ((e == thi0) ? amp0 : 0.0f);
            a1[j] += ((e == tlo1) ? amp1 : 0.0f) + ((e == thi1) ? amp1 : 0.0f);
        }

        __builtin_nontemporal_store(a0, (f32x4*)(ot0 + e0));
        __builtin_nontemporal_store(a1, (f32x4*)(ot0 + D + e0));

        if (!more) break;
        a0 = na0; c0 = nc0; a1 = na1; c1 = nc1;
        p = pn;
    }
}

extern "C" void kernel_launch(void* const* d_in, const int* in_sizes, int n_in,
                              void* d_out, int out_size, void* d_ws, size_t ws_size,
                              hipStream_t stream)
{
    const float* x = (const float*)d_in[0];
    float* out = (float*)d_out;
    const int ntok = in_sizes[0] / D;   // 262144

    // Occupancy sweep: 32 w/CU = 188.0 us, 8 w/CU = 179.5 us, now 4 w/CU.
    // Latency-hiding needs only ~9 KB reads in flight per CU; each wave holds
    // 8 KB -> 4 waves/CU still covers, with less VMEM queue contention.
    const int block = 256;              // 4 waves/block
    const int grid  = 256;              // 1024 waves; 128 pairs per wave (exact)
    shift_ffn_kernel<<<grid, block, 0, stream>>>(x, out, ntok);
}

// Round 8
// 188.434 us; speedup vs baseline: 1.0555x; 1.0555x over previous
//
#include <hip/hip_runtime.h>

// BD-format field offsets (D = 512)
#define MARK_AX      0
#define OP_SHL       39   // elem 39 = 4*9 + 3  -> ballot[3] bit 9
#define OP_SHR       40   // elem 40 = 4*10 + 0 -> ballot[0] bit 10
#define ALU_LO       64   // lanes 16..19
#define ALU_HI       80   // lanes 20..23
#define AX_CARRY_LO  96   // lanes 24..27
#define OUTPUT_LO    128
#define OUTPUT_HI    144

constexpr int D = 512;

typedef float f32x4 __attribute__((ext_vector_type(4)));

// First hot index (0 if none) of the 16-wide field whose elements live in
// lanes [lane0, lane0+4). elem = 4*l + j  ->  field idx k = 4*(l-lane0) + j.
__device__ __forceinline__ int first_hot(const unsigned long long b[4], int lane0) {
    int best = 999;
    #pragma unroll
    for (int j = 0; j < 4; ++j) {
        unsigned nib = (unsigned)(b[j] >> lane0) & 0xFu;
        int cand = nib ? (4 * (__ffs(nib) - 1) + j) : 999;
        best = min(best, cand);
    }
    return (best >= 16) ? 0 : best;   // argmax-of-bool: 0 when no bit set
}

__device__ __forceinline__ void decode(const unsigned long long b[4],
                                       int& tlo, int& thi, float& amp) {
    const bool mark = (b[0] >> 0) & 1ull;    // elem 0
    const bool shl  = (b[3] >> 9) & 1ull;    // elem 39
    const bool shr  = (b[0] >> 10) & 1ull;   // elem 40

    const int lo = first_hot(b, 16);         // elems 64..79
    const int hi = first_hot(b, 20);         // elems 80..95
    const int sa = first_hot(b, 24);         // elems 96..111

    const int  val     = lo + 16 * hi;
    const bool act_shl = mark && shl;
    const bool act_shr = mark && shr && !shl;  // elif priority

    const int res = act_shl ? ((val << sa) & 0xFF)
                  : (act_shr ? (val >> sa) : 0);

    tlo = OUTPUT_LO + (res & 15);
    thi = OUTPUT_HI + (res >> 4);
    amp = (act_shl || act_shr) ? 2.0f : 0.0f;
}

__global__ __launch_bounds__(256) void shift_ffn_kernel(
    const float* __restrict__ x, float* __restrict__ out, int ntok)
{
    const int lane = threadIdx.x & 63;
    const int wid  = (blockIdx.x * blockDim.x + threadIdx.x) >> 6;
    const int nw   = (gridDim.x * blockDim.x) >> 6;
    const int e0   = 4 * lane;
    const int npair = ntok >> 1;              // ntok is even (8*32768)

    int p = wid;
    if (p >= npair) return;

    // Prologue: load first pair (2 tokens, 2 halves each); nt loads AND nt
    // stores (R2-R5 A/B: full L2 bypass both directions is fastest).
    const float* xt0 = x + (size_t)(2 * p) * D;
    f32x4 a0 = __builtin_nontemporal_load((const f32x4*)(xt0 + e0));
    f32x4 c0 = __builtin_nontemporal_load((const f32x4*)(xt0 + 256 + e0));
    f32x4 a1 = __builtin_nontemporal_load((const f32x4*)(xt0 + D + e0));
    f32x4 c1 = __builtin_nontemporal_load((const f32x4*)(xt0 + D + 256 + e0));

    while (true) {
        // Software pipeline: issue next iteration's 4 loads BEFORE consuming
        // the current ones. `more` is wave-uniform -> no divergence.
        const int pn = p + nw;
        const bool more = (pn < npair);
        f32x4 na0, nc0, na1, nc1;
        if (more) {
            const float* xn = x + (size_t)(2 * pn) * D;
            na0 = __builtin_nontemporal_load((const f32x4*)(xn + e0));
            nc0 = __builtin_nontemporal_load((const f32x4*)(xn + 256 + e0));
            na1 = __builtin_nontemporal_load((const f32x4*)(xn + D + e0));
            nc1 = __builtin_nontemporal_load((const f32x4*)(xn + D + 256 + e0));
        }

        // Ballot-based control gather: b[j] bit l == (elem 4l+j > 0.5)
        unsigned long long b0[4], b1[4];
        #pragma unroll
        for (int j = 0; j < 4; ++j) b0[j] = __ballot(a0[j] > 0.5f);
        #pragma unroll
        for (int j = 0; j < 4; ++j) b1[j] = __ballot(a1[j] > 0.5f);

        float* ot0 = out + (size_t)(2 * p) * D;

        // c-half stores are decode-independent: issue them first.
        __builtin_nontemporal_store(c0, (f32x4*)(ot0 + 256 + e0));
        __builtin_nontemporal_store(c1, (f32x4*)(ot0 + D + 256 + e0));

        int tlo0, thi0, tlo1, thi1; float amp0, amp1;
        decode(b0, tlo0, thi0, amp0);
        decode(b1, tlo1, thi1, amp1);

        #pragma unroll
        for (int j = 0; j < 4; ++j) {
            const int e = e0 + j;
            a0[j] += ((e == tlo0) ? amp0 : 0.0f) + ((e == thi0) ? amp0 : 0.0f);
            a1[j] += ((e == tlo1) ? amp1 : 0.0f) + ((e == thi1) ? amp1 : 0.0f);
        }

        __builtin_nontemporal_store(a0, (f32x4*)(ot0 + e0));
        __builtin_nontemporal_store(a1, (f32x4*)(ot0 + D + e0));

        if (!more) break;
        a0 = na0; c0 = nc0; a1 = na1; c1 = nc1;
        p = pn;
    }
}

extern "C" void kernel_launch(void* const* d_in, const int* in_sizes, int n_in,
                              void* d_out, int out_size, void* d_ws, size_t ws_size,
                              hipStream_t stream)
{
    const float* x = (const float*)d_in[0];
    float* out = (float*)d_out;
    const int ntok = in_sizes[0] / D;   // 262144

    // Occupancy sweep: 4 w/CU = 198.9, 8 w/CU = 179.5, 32 w/CU = 188.0.
    // Final probe: 16 w/CU (grid=1024) to bracket the minimum.
    const int block = 256;              // 4 waves/block
    const int grid  = 1024;             // 4096 waves; 32 pairs per wave (exact)
    shift_ffn_kernel<<<grid, block, 0, stream>>>(x, out, ntok);
}

// Round 9
// 177.288 us; speedup vs baseline: 1.1219x; 1.0629x over previous
//
#include <hip/hip_runtime.h>

// BD-format field offsets (D = 512)
#define MARK_AX      0
#define OP_SHL       39   // elem 39 = 4*9 + 3  -> ballot[3] bit 9
#define OP_SHR       40   // elem 40 = 4*10 + 0 -> ballot[0] bit 10
#define ALU_LO       64   // lanes 16..19
#define ALU_HI       80   // lanes 20..23
#define AX_CARRY_LO  96   // lanes 24..27
#define OUTPUT_LO    128
#define OUTPUT_HI    144

constexpr int D = 512;

typedef float f32x4 __attribute__((ext_vector_type(4)));

// First hot index (0 if none) of the 16-wide field whose elements live in
// lanes [lane0, lane0+4). elem = 4*l + j  ->  field idx k = 4*(l-lane0) + j.
__device__ __forceinline__ int first_hot(const unsigned long long b[4], int lane0) {
    int best = 999;
    #pragma unroll
    for (int j = 0; j < 4; ++j) {
        unsigned nib = (unsigned)(b[j] >> lane0) & 0xFu;
        int cand = nib ? (4 * (__ffs(nib) - 1) + j) : 999;
        best = min(best, cand);
    }
    return (best >= 16) ? 0 : best;   // argmax-of-bool: 0 when no bit set
}

__device__ __forceinline__ void decode(const unsigned long long b[4],
                                       int& tlo, int& thi, float& amp) {
    const bool mark = (b[0] >> 0) & 1ull;    // elem 0
    const bool shl  = (b[3] >> 9) & 1ull;    // elem 39
    const bool shr  = (b[0] >> 10) & 1ull;   // elem 40

    const int lo = first_hot(b, 16);         // elems 64..79
    const int hi = first_hot(b, 20);         // elems 80..95
    const int sa = first_hot(b, 24);         // elems 96..111

    const int  val     = lo + 16 * hi;
    const bool act_shl = mark && shl;
    const bool act_shr = mark && shr && !shl;  // elif priority

    const int res = act_shl ? ((val << sa) & 0xFF)
                  : (act_shr ? (val >> sa) : 0);

    tlo = OUTPUT_LO + (res & 15);
    thi = OUTPUT_HI + (res >> 4);
    amp = (act_shl || act_shr) ? 2.0f : 0.0f;
}

__global__ __launch_bounds__(256) void shift_ffn_kernel(
    const float* __restrict__ x, float* __restrict__ out, int ntok)
{
    const int lane = threadIdx.x & 63;
    const int wid  = (blockIdx.x * blockDim.x + threadIdx.x) >> 6;
    const int nw   = (gridDim.x * blockDim.x) >> 6;
    const int e0   = 4 * lane;
    const int npair = ntok >> 1;              // ntok is even (8*32768)

    int p = wid;
    if (p >= npair) return;

    // Prologue: load first pair (2 tokens, 2 halves each); nt loads AND nt
    // stores (R2-R5 A/B: full L2 bypass both directions is fastest).
    const float* xt0 = x + (size_t)(2 * p) * D;
    f32x4 a0 = __builtin_nontemporal_load((const f32x4*)(xt0 + e0));
    f32x4 c0 = __builtin_nontemporal_load((const f32x4*)(xt0 + 256 + e0));
    f32x4 a1 = __builtin_nontemporal_load((const f32x4*)(xt0 + D + e0));
    f32x4 c1 = __builtin_nontemporal_load((const f32x4*)(xt0 + D + 256 + e0));

    while (true) {
        // Software pipeline: issue next iteration's 4 loads BEFORE consuming
        // the current ones. `more` is wave-uniform -> no divergence.
        const int pn = p + nw;
        const bool more = (pn < npair);
        f32x4 na0, nc0, na1, nc1;
        if (more) {
            const float* xn = x + (size_t)(2 * pn) * D;
            na0 = __builtin_nontemporal_load((const f32x4*)(xn + e0));
            nc0 = __builtin_nontemporal_load((const f32x4*)(xn + 256 + e0));
            na1 = __builtin_nontemporal_load((const f32x4*)(xn + D + e0));
            nc1 = __builtin_nontemporal_load((const f32x4*)(xn + D + 256 + e0));
        }

        // Ballot-based control gather: b[j] bit l == (elem 4l+j > 0.5)
        unsigned long long b0[4], b1[4];
        #pragma unroll
        for (int j = 0; j < 4; ++j) b0[j] = __ballot(a0[j] > 0.5f);
        #pragma unroll
        for (int j = 0; j < 4; ++j) b1[j] = __ballot(a1[j] > 0.5f);

        float* ot0 = out + (size_t)(2 * p) * D;

        // c-half stores are decode-independent: issue them first.
        __builtin_nontemporal_store(c0, (f32x4*)(ot0 + 256 + e0));
        __builtin_nontemporal_store(c1, (f32x4*)(ot0 + D + 256 + e0));

        int tlo0, thi0, tlo1, thi1; float amp0, amp1;
        decode(b0, tlo0, thi0, amp0);
        decode(b1, tlo1, thi1, amp1);

        #pragma unroll
        for (int j = 0; j < 4; ++j) {
            const int e = e0 + j;
            a0[j] += ((e == tlo0) ? amp0 : 0.0f) + ((e == thi0) ? amp0 : 0.0f);
            a1[j] += ((e == tlo1) ? amp1 : 0.0f) + ((e == thi1) ? amp1 : 0.0f);
        }

        __builtin_nontemporal_store(a0, (f32x4*)(ot0 + e0));
        __builtin_nontemporal_store(a1, (f32x4*)(ot0 + D + e0));

        if (!more) break;
        a0 = na0; c0 = nc0; a1 = na1; c1 = nc1;
        p = pn;
    }
}

extern "C" void kernel_launch(void* const* d_in, const int* in_sizes, int n_in,
                              void* d_out, int out_size, void* d_ws, size_t ws_size,
                              hipStream_t stream)
{
    const float* x = (const float*)d_in[0];
    float* out = (float*)d_out;
    const int ntok = in_sizes[0] / D;   // 262144

    // Occupancy sweep complete: 4 w/CU = 198.9, 8 w/CU = 179.5 (BEST),
    // 16 w/CU = 188.4, 32 w/CU = 188.0. Pin the minimum: grid=512.
    const int block = 256;              // 4 waves/block
    const int grid  = 512;              // 2048 waves = 8 w/CU; 64 pairs/wave
    shift_ffn_kernel<<<grid, block, 0, stream>>>(x, out, ntok);
}